// Round 10
// baseline (36.293 us; speedup 1.0000x reference)
//
#include <hip/hip_runtime.h>
#include <math.h>

#define KPOOL 16
#define SPLIT 2  // threads cooperating on one graph (long streams)

typedef float f32x4 __attribute__((ext_vector_type(4)));

__device__ __forceinline__ void ce(float& x, float& y) {
  float hi = fmaxf(x, y), lo = fminf(x, y);
  x = hi;
  y = lo;
}

// Batcher odd-even mergesort, 8 inputs, 19 CEs, descending.
__device__ __forceinline__ void sort8(float (&v)[8]) {
  ce(v[0], v[1]); ce(v[2], v[3]); ce(v[4], v[5]); ce(v[6], v[7]);
  ce(v[0], v[2]); ce(v[1], v[3]); ce(v[4], v[6]); ce(v[5], v[7]);
  ce(v[1], v[2]); ce(v[5], v[6]);
  ce(v[0], v[4]); ce(v[1], v[5]); ce(v[2], v[6]); ce(v[3], v[7]);
  ce(v[2], v[4]); ce(v[3], v[5]);
  ce(v[1], v[2]); ce(v[3], v[4]); ce(v[5], v[6]);
}

// t sorted-16 desc, b sorted-8 desc -> t = top-16 of union, sorted.
__device__ __forceinline__ void merge8into16(float (&t)[KPOOL], const float (&b)[8]) {
#pragma unroll
  for (int i = 8; i < 16; ++i) t[i] = fmaxf(t[i], b[15 - i]);
#pragma unroll
  for (int s = 8; s >= 1; s >>= 1) {
#pragma unroll
    for (int i = 0; i < 16; ++i)
      if ((i & s) == 0) ce(t[i], t[i + s]);
  }
}

// Merge this lane's sorted-16 with lane^dist's: top-16 of union.
__device__ __forceinline__ void merge_partner(float (&t)[KPOOL], int dist) {
  float c[KPOOL];
#pragma unroll
  for (int i = 0; i < KPOOL; ++i) {
    float o = __shfl_xor(t[KPOOL - 1 - i], dist);
    c[i] = fmaxf(t[i], o);
  }
#pragma unroll
  for (int s = 8; s >= 1; s >>= 1) {
#pragma unroll
    for (int i = 0; i < KPOOL; ++i)
      if ((i & s) == 0) ce(c[i], c[i + s]);
  }
#pragma unroll
  for (int i = 0; i < KPOOL; ++i) t[i] = c[i];
}

__device__ __forceinline__ int lb_range(const int* __restrict__ a, int lo,
                                        int hi, int key) {
  while (lo < hi) {
    int mid = (lo + hi) >> 1;
    if (a[mid] < key) lo = mid + 1;
    else hi = mid;
  }
  return lo;
}

// Exact lower_bound via batched 8-ary search (7 independent probes/round over
// a +-16384 = 8-sigma verified window; full-range fallback for exactness).
__global__ __launch_bounds__(256)
void boundary_kernel(const int* __restrict__ emap, int total, int n,
                     int* __restrict__ starts, float* __restrict__ wn_out,
                     const float* __restrict__ W) {
  const int g = blockIdx.x * 256 + threadIdx.x;
  if (g == 0) {  // softmax(W), grid-uniform
    float w[KPOOL], m = -INFINITY, s = 0.0f;
#pragma unroll
    for (int k = 0; k < KPOOL; ++k) { w[k] = W[k]; m = fmaxf(m, w[k]); }
#pragma unroll
    for (int k = 0; k < KPOOL; ++k) { w[k] = expf(w[k] - m); s += w[k]; }
#pragma unroll
    for (int k = 0; k < KPOOL; ++k) wn_out[k] = w[k] / s;
  }
  if (g > n) return;
  if (g == 0) { starts[0] = 0; return; }       // e_map values >= 0
  if (g >= n) { starts[n] = total; return; }   // e_map values < n

  const int key = g;
  const int W0 = 32768;
  if (total < W0) { starts[g] = lb_range(emap, 0, total, key); return; }

  long long E = (long long)key * total / n;
  int wlo = (int)(E - W0 / 2);
  if (wlo < 0) wlo = 0;
  if (wlo > total - W0) wlo = total - W0;

  int p[7];
#pragma unroll
  for (int k = 0; k < 7; ++k) p[k] = emap[wlo + (k + 1) * 4096];
  const int vlo = (wlo > 0) ? emap[wlo - 1] : key - 1 - key;  // force "< key"
  const int vhi = emap[wlo + W0 - 1];
  const bool ok = (vlo < key) && ((wlo + W0 == total) || (vhi >= key));
  if (!ok) { starts[g] = lb_range(emap, 0, total, key); return; }

  int lo = wlo;
  int c = 0;
#pragma unroll
  for (int k = 0; k < 7; ++k) c += (p[k] < key) ? 1 : 0;
  lo += c * 4096;

#pragma unroll
  for (int w8 = 512; w8 >= 1; w8 >>= 3) {
#pragma unroll
    for (int k = 0; k < 7; ++k) p[k] = emap[lo + (k + 1) * w8];
    c = 0;
#pragma unroll
    for (int k = 0; k < 7; ++k) c += (p[k] < key) ? 1 : 0;
    lo += c * w8;
  }
  starts[g] = (emap[lo] < key) ? lo + 1 : lo;
}

// Load one aligned 8-elem block (two dwordx4), clamped in-bounds.
#define LOADB(R0, R1, bb)                                              \
  {                                                                    \
    const int cb_ = (bb) <= BLAST ? (bb) : BLAST;                      \
    const f32x4* p_ = reinterpret_cast<const f32x4*>(Y + (cb_ << 3));  \
    R0 = p_[0];                                                        \
    R1 = p_[1];                                                        \
  }

// Consume buffer (waits only ITS load), immediately refill it for batch nb,
// then mask+sort+merge. No cross-buffer register rotation anywhere -> the
// compiler can use partial vmcnt waits and keep 3 other buffers in flight.
#define STEPP(R0, R1, bb, nb)                                          \
  {                                                                    \
    float v[8] = {R0[0], R0[1], R0[2], R0[3], R1[0], R1[1], R1[2], R1[3]}; \
    LOADB(R0, R1, nb);                                                 \
    const int base_ = (bb) << 3;                                       \
    if (base_ < s0 || base_ + 8 > s1) {                                \
      _Pragma("unroll") for (int jj = 0; jj < 8; ++jj) {               \
        int idx_ = base_ + jj;                                         \
        if (idx_ < s0 || idx_ >= s1) v[jj] = -INFINITY;                \
      }                                                                \
    }                                                                  \
    sort8(v);                                                          \
    merge8into16(t, v);                                                \
  }

// Scan this thread's batch stream (blocks B0+q, step SPLIT) with a 4-buffer
// rotation-free software pipeline; merge results into t[16].
__device__ __forceinline__ void scan_segment(const float* __restrict__ Y,
                                             int s0, int s1, int q, int total,
                                             float (&t)[KPOOL]) {
  const int B0 = s0 >> 3;
  const int B1 = (s1 + 7) >> 3;
  const int BLAST = (total >> 3) - 1;

  int b = B0 + q;
  f32x4 A0, A1, Bb0, Bb1, C0, C1, D0, D1;
  LOADB(A0, A1, b);
  LOADB(Bb0, Bb1, b + SPLIT);
  LOADB(C0, C1, b + 2 * SPLIT);
  LOADB(D0, D1, b + 3 * SPLIT);
#pragma unroll 1
  while (b < B1) {
    STEPP(A0, A1, b, b + 4 * SPLIT);
    STEPP(Bb0, Bb1, b + SPLIT, b + 5 * SPLIT);
    STEPP(C0, C1, b + 2 * SPLIT, b + 6 * SPLIT);
    STEPP(D0, D1, b + 3 * SPLIT, b + 7 * SPLIT);
    b += 4 * SPLIT;
  }
}

__global__ __launch_bounds__(128, 4)
void sortpool_main(const float* __restrict__ Y,
                   const int* __restrict__ starts,
                   const float* __restrict__ Wn,
                   float* __restrict__ out, int total, int n) {
  const int tid = blockIdx.x * 128 + threadIdx.x;
  const int g = tid >> 1;  // graph id; 2 consecutive lanes share a graph
  const int q = tid & 1;   // stride id
  if (g >= n) return;

  const int s0 = starts[g];
  const int s1 = starts[g + 1];

  float t[KPOOL];
#pragma unroll
  for (int i = 0; i < KPOOL; ++i) t[i] = -INFINITY;

  scan_segment(Y, s0, s1, q, total, t);

  // combine the 2 strides' sorted-16 lists (1 butterfly level)
  merge_partner(t, 1);

  // weighted sum with precomputed softmax(W); -inf slots (exhausted) -> 0
  float res = 0.0f;
#pragma unroll
  for (int k = 0; k < KPOOL; ++k) {
    float tv = t[k];
    res += (tv > -INFINITY) ? tv * Wn[k] : 0.0f;
  }

  if (q == 0) out[g] = res;
}

// Fallback main (no workspace): per-thread full binary search, same scan.
__global__ __launch_bounds__(128, 4)
void sortpool_main_nows(const float* __restrict__ Y, const float* __restrict__ W,
                        const int* __restrict__ emap, float* __restrict__ out,
                        int total, int n) {
  const int tid = blockIdx.x * 128 + threadIdx.x;
  const int g = tid >> 1;
  const int q = tid & 1;
  if (g >= n) return;
  const int s0 = lb_range(emap, 0, total, g);
  const int s1 = lb_range(emap, 0, total, g + 1);
  float t[KPOOL];
#pragma unroll
  for (int i = 0; i < KPOOL; ++i) t[i] = -INFINITY;
  scan_segment(Y, s0, s1, q, total, t);
  merge_partner(t, 1);
  float wv[KPOOL], m = -INFINITY, s = 0.0f;
#pragma unroll
  for (int k = 0; k < KPOOL; ++k) { wv[k] = W[k]; m = fmaxf(m, wv[k]); }
#pragma unroll
  for (int k = 0; k < KPOOL; ++k) { wv[k] = expf(wv[k] - m); s += wv[k]; }
  const float inv = 1.0f / s;
  float res = 0.0f;
#pragma unroll
  for (int k = 0; k < KPOOL; ++k) {
    float tv = t[k];
    res += (tv > -INFINITY) ? tv * (wv[k] * inv) : 0.0f;
  }
  if (q == 0) out[g] = res;
}

extern "C" void kernel_launch(void* const* d_in, const int* in_sizes, int n_in,
                              void* d_out, int out_size, void* d_ws, size_t ws_size,
                              hipStream_t stream) {
  const float* Y = (const float*)d_in[0];   // [TOTAL]
  const float* W = (const float*)d_in[1];   // [16]
  const int* emap = (const int*)d_in[2];    // [TOTAL], sorted
  const int total = in_sizes[0];
  const int n = in_sizes[3];                // len(v_count)
  float* out = (float*)d_out;               // [N] float32

  int* starts = (int*)d_ws;
  float* wn_buf = (float*)((char*)d_ws + (size_t)(n + 1) * sizeof(int));
  const bool use_ws =
      (ws_size >= (size_t)(n + 1) * sizeof(int) + KPOOL * sizeof(float));

  long long threads = (long long)n * SPLIT;
  int blocks = (int)((threads + 127) / 128);

  if (use_ws) {
    int nb = (n + 1 + 255) / 256;
    boundary_kernel<<<nb, 256, 0, stream>>>(emap, total, n, starts, wn_buf, W);
    sortpool_main<<<blocks, 128, 0, stream>>>(Y, starts, wn_buf, out, total, n);
  } else {
    sortpool_main_nows<<<blocks, 128, 0, stream>>>(Y, W, emap, out, total, n);
  }
}